// Round 5
// baseline (19.192 us; speedup 1.0000x reference)
//
#include <hip/hip_runtime.h>

// BatchAllTripletLoss, B=512, E=128, labels in [0,64), MARGIN=1.0, EPS=1e-16.
// out = sum(hinge) / (count(hinge > EPS) + EPS) over valid (a,p,n).
//
// K1 pos_dists:  posd[a][i] = ||e_a - e_{p_i}||^2 for each positive p_i of a
//                (ballot-compacted list), npos[a]. 512 blocks.
// K2 hinge_tiles: 16x16 grid of 32x32 (anchor x negative) tiles. Staging +
//                2x2 register dist like dist_tiles, then hinge accumulated
//                in-register against LDS posd. 256 partials to d_ws.
// K3 finalize:   one block reduces 256 partials, writes out[0].
// No atomics anywhere -> deterministic.

#define BSZ 512
#define EDIM 128
#define TS 32
#define NPOSMAX 64

__global__ __launch_bounds__(256) void pos_dists(
    const float* __restrict__ embs,
    const int* __restrict__ labels,
    float* __restrict__ posd,
    int* __restrict__ npos)
{
    __shared__ int lab[BSZ];
    __shared__ unsigned long long masks[8];
    __shared__ int plist[NPOSMAX];

    const int a = blockIdx.x, tid = threadIdx.x;
    const int wv = tid >> 6, lane = tid & 63;

    lab[tid]       = labels[tid];
    lab[tid + 256] = labels[tid + 256];
    __syncthreads();

    const int la = lab[a];

#pragma unroll
    for (int c = 0; c < 2; ++c) {
        int j = c * 256 + tid;
        unsigned long long m = __ballot(lab[j] == la && j != a);
        if (lane == 0) masks[c * 4 + wv] = m;
    }
    __syncthreads();

    int np = 0;
#pragma unroll
    for (int m = 0; m < 8; ++m) np += __popcll(masks[m]);
    if (np > NPOSMAX) np = NPOSMAX;

#pragma unroll
    for (int c = 0; c < 2; ++c) {
        int j = c * 256 + tid;
        if (lab[j] == la && j != a) {
            int mi = c * 4 + wv, off = 0;
            for (int m = 0; m < mi; ++m) off += __popcll(masks[m]);
            off += __popcll(masks[mi] & ((1ull << lane) - 1ull));
            if (off < NPOSMAX) plist[off] = j;
        }
    }
    if (tid == 0) npos[a] = np;
    __syncthreads();

    // One wave per positive: lane covers 2 dims via float2, shuffle-reduce.
    float2 av = reinterpret_cast<const float2*>(embs + (size_t)a * EDIM)[lane];
    for (int i = wv; i < np; i += 4) {
        int p = plist[i];
        float2 pv = reinterpret_cast<const float2*>(embs + (size_t)p * EDIM)[lane];
        float dx = av.x - pv.x, dy = av.y - pv.y;
        float t = dx * dx + dy * dy;
#pragma unroll
        for (int off = 32; off; off >>= 1) t += __shfl_xor(t, off);
        if (lane == 0) posd[(size_t)a * NPOSMAX + i] = t;
    }
}

__global__ __launch_bounds__(256) void hinge_tiles(
    const float* __restrict__ embs,
    const int* __restrict__ labels,
    const float* __restrict__ posd,
    const int* __restrict__ npos,
    float* __restrict__ sums,
    float* __restrict__ cnts)
{
    __shared__ float At[TS][EDIM + 4];
    __shared__ float Bt[TS][EDIM + 4];
    __shared__ float nA[TS], nB[TS];
    __shared__ float psh[TS][NPOSMAX + 1];
    __shared__ int   npsh[TS];
    __shared__ int   labI[TS], labJ[TS];
    __shared__ float wsum[4];
    __shared__ int   wcnt[4];

    const int tid = threadIdx.x;
    const int bi = blockIdx.x >> 4;
    const int bj = blockIdx.x & 15;
    const int I = bi * TS, J = bj * TS;
    const int wv = tid >> 6, lane = tid & 63;

    // Stage A/B tiles, coalesced float4.
#pragma unroll
    for (int q = 0; q < 4; ++q) {
        int idx = tid + 256 * q;
        int r   = idx >> 5;
        int k4  = idx & 31;
        float4 va = reinterpret_cast<const float4*>(embs + (size_t)(I + r) * EDIM)[k4];
        *reinterpret_cast<float4*>(&At[r][k4 * 4]) = va;
        float4 vb = reinterpret_cast<const float4*>(embs + (size_t)(J + r) * EDIM)[k4];
        *reinterpret_cast<float4*>(&Bt[r][k4 * 4]) = vb;
    }
    // posd tile: 32 x 64 floats, 8 per thread, coalesced.
#pragma unroll
    for (int q = 0; q < 8; ++q) {
        int idx = tid + 256 * q;          // 0..2047
        int r = idx >> 6, p = idx & 63;
        psh[r][p] = posd[(size_t)(I + r) * NPOSMAX + p];
    }
    if (tid < TS) { npsh[tid] = npos[I + tid]; labI[tid] = labels[I + tid]; }
    else if (tid < 2 * TS) { labJ[tid - TS] = labels[J + tid - TS]; }
    __syncthreads();

    // Row norms (threads 0..63).
    if (tid < 64) {
        int r = tid & 31;
        float s = 0.f;
        if (tid < 32) {
#pragma unroll
            for (int k = 0; k < EDIM; k += 4) {
                float4 v = *reinterpret_cast<float4*>(&At[r][k]);
                s += v.x * v.x + v.y * v.y + v.z * v.z + v.w * v.w;
            }
            nA[r] = s;
        } else {
#pragma unroll
            for (int k = 0; k < EDIM; k += 4) {
                float4 v = *reinterpret_cast<float4*>(&Bt[r][k]);
                s += v.x * v.x + v.y * v.y + v.z * v.z + v.w * v.w;
            }
            nB[r] = s;
        }
    }
    __syncthreads();

    // 2x2 register-blocked dists.
    const int tr = tid >> 4, tc = tid & 15;
    float a00 = 0.f, a01 = 0.f, a10 = 0.f, a11 = 0.f;
#pragma unroll 8
    for (int k = 0; k < EDIM; k += 4) {
        float4 x0 = *reinterpret_cast<float4*>(&At[tr][k]);
        float4 x1 = *reinterpret_cast<float4*>(&At[tr + 16][k]);
        float4 y0 = *reinterpret_cast<float4*>(&Bt[tc][k]);
        float4 y1 = *reinterpret_cast<float4*>(&Bt[tc + 16][k]);
        a00 += x0.x * y0.x + x0.y * y0.y + x0.z * y0.z + x0.w * y0.w;
        a01 += x0.x * y1.x + x0.y * y1.y + x0.z * y1.z + x0.w * y1.w;
        a10 += x1.x * y0.x + x1.y * y0.y + x1.z * y0.z + x1.w * y0.w;
        a11 += x1.x * y1.x + x1.y * y1.y + x1.z * y1.z + x1.w * y1.w;
    }
    float d00 = fmaxf(nA[tr]      + nB[tc]      - 2.f * a00, 0.f);
    float d01 = fmaxf(nA[tr]      + nB[tc + 16] - 2.f * a01, 0.f);
    float d10 = fmaxf(nA[tr + 16] + nB[tc]      - 2.f * a10, 0.f);
    float d11 = fmaxf(nA[tr + 16] + nB[tc + 16] - 2.f * a11, 0.f);

    // Hinge accumulation against LDS posd.
    const int la0 = labI[tr], la1 = labI[tr + 16];
    const int ln0 = labJ[tc], ln1 = labJ[tc + 16];
    const int np0 = npsh[tr], np1 = npsh[tr + 16];

    float s = 0.f;
    int   c = 0;
    if (ln0 != la0) {
        for (int p = 0; p < np0; ++p) {
            float t = fmaxf(psh[tr][p] - d00 + 1.0f, 0.f);
            s += t; c += (t > 1e-16f) ? 1 : 0;
        }
    }
    if (ln1 != la0) {
        for (int p = 0; p < np0; ++p) {
            float t = fmaxf(psh[tr][p] - d01 + 1.0f, 0.f);
            s += t; c += (t > 1e-16f) ? 1 : 0;
        }
    }
    if (ln0 != la1) {
        for (int p = 0; p < np1; ++p) {
            float t = fmaxf(psh[tr + 16][p] - d10 + 1.0f, 0.f);
            s += t; c += (t > 1e-16f) ? 1 : 0;
        }
    }
    if (ln1 != la1) {
        for (int p = 0; p < np1; ++p) {
            float t = fmaxf(psh[tr + 16][p] - d11 + 1.0f, 0.f);
            s += t; c += (t > 1e-16f) ? 1 : 0;
        }
    }

    // Block reduction.
#pragma unroll
    for (int off = 32; off; off >>= 1) {
        s += __shfl_down(s, off);
        c += __shfl_down(c, off);
    }
    if (lane == 0) { wsum[wv] = s; wcnt[wv] = c; }
    __syncthreads();
    if (tid == 0) {
        sums[blockIdx.x] = wsum[0] + wsum[1] + wsum[2] + wsum[3];
        cnts[blockIdx.x] = (float)(wcnt[0] + wcnt[1] + wcnt[2] + wcnt[3]);
    }
}

__global__ __launch_bounds__(256) void finalize(
    const float* __restrict__ sums,
    const float* __restrict__ cnts,
    float* __restrict__ out)
{
    __shared__ float wsum[4], wcnt[4];
    const int tid = threadIdx.x;
    float s = sums[tid];
    float c = cnts[tid];
#pragma unroll
    for (int off = 32; off; off >>= 1) {
        s += __shfl_down(s, off);
        c += __shfl_down(c, off);
    }
    const int wv = tid >> 6, lane = tid & 63;
    if (lane == 0) { wsum[wv] = s; wcnt[wv] = c; }
    __syncthreads();
    if (tid == 0) {
        float S = wsum[0] + wsum[1] + wsum[2] + wsum[3];
        float C = wcnt[0] + wcnt[1] + wcnt[2] + wcnt[3];
        out[0] = S / (C + 1e-16f);
    }
}

extern "C" void kernel_launch(void* const* d_in, const int* in_sizes, int n_in,
                              void* d_out, int out_size, void* d_ws, size_t ws_size,
                              hipStream_t stream)
{
    const float* embs   = reinterpret_cast<const float*>(d_in[0]);
    const int*   labels = reinterpret_cast<const int*>(d_in[1]);
    float*       out    = reinterpret_cast<float*>(d_out);

    float* posd  = reinterpret_cast<float*>(d_ws);            // 512*64*4 = 128 KB
    int*   npos  = reinterpret_cast<int*>(posd + (size_t)BSZ * NPOSMAX);  // 2 KB
    float* sums  = reinterpret_cast<float*>(npos + BSZ);      // 1 KB
    float* cnts  = sums + 256;                                // 1 KB

    pos_dists<<<BSZ, 256, 0, stream>>>(embs, labels, posd, npos);
    hinge_tiles<<<256, 256, 0, stream>>>(embs, labels, posd, npos, sums, cnts);
    finalize<<<1, 256, 0, stream>>>(sums, cnts, out);
}